// Round 14
// baseline (228.217 us; speedup 1.0000x reference)
//
#include <hip/hip_runtime.h>
#include <hip/hip_bf16.h>
#include <stdint.h>

// MultiHeadAttention: x[4,2048,1024] fp32, mask[4,2048] i32,
// w_qkv[3072,1024], w_tail[1024,1024], b_tail[1024] -> out[4,2048,1024] fp32
// Pipeline: fused cvt->bf16; GEMM1 = 256x128 BK=32 depth-2 (2 blocks/CU);
// GEMM2 = 256x128 BK=64 depth-2; attn = two-tile pipeline with 64 q-rows
// per wave (QBLK=256/block, grid 512 = one exact dispatch round; K/V LDS
// fragment reads amortized over 2x MFMA).

typedef __attribute__((ext_vector_type(8))) short short8;
typedef __attribute__((ext_vector_type(4))) short short4b;
typedef __attribute__((ext_vector_type(4))) float f32x4;

#define T_SEQ 2048
#define NHEAD 16
#define DHEAD 64
#define DMODEL 1024

#if __has_builtin(__builtin_amdgcn_exp2f)
#define EXP2(x) __builtin_amdgcn_exp2f(x)
#else
#define EXP2(x) exp2f(x)
#endif

__device__ __forceinline__ ushort f2bf(float f) {
  __bf16 h = (__bf16)f;
  unsigned short u;
  __builtin_memcpy(&u, &h, 2);
  return u;
}
__device__ __forceinline__ float bf2f(ushort b) {
  return __uint_as_float(((uint32_t)b) << 16);
}

// sigma-perm within a 64-column tile; inverse (kv -> stored pos):
__device__ __forceinline__ int permInv(int x) {
  return (x & 0x23) | ((x & 0x0C) << 1) | ((x & 0x10) >> 2);
}

__device__ __forceinline__ void gload_lds16(const ushort* g, ushort* l) {
  __builtin_amdgcn_global_load_lds(
      (const __attribute__((address_space(1))) void*)g,
      (__attribute__((address_space(3))) void*)l, 16, 0, 0);
}

// ---------------- fused fp32 -> bf16 conversion (x | w_qkv | w_tail) -------
__global__ void cvt_all(const float* __restrict__ x,
                        const float* __restrict__ wq,
                        const float* __restrict__ wt,
                        ushort* __restrict__ out,
                        int n8x, int n8q, int n8t) {
  int i = blockIdx.x * blockDim.x + threadIdx.x;
  const float* src;
  int j;
  if (i < n8x) { src = x; j = i; }
  else if (i < n8x + n8q) { src = wq; j = i - n8x; }
  else if (i < n8x + n8q + n8t) { src = wt; j = i - n8x - n8q; }
  else return;
  const float4* p = (const float4*)(src + (size_t)j * 8);
  float4 a = p[0], b = p[1];
  short8 o;
  o[0] = (short)f2bf(a.x); o[1] = (short)f2bf(a.y);
  o[2] = (short)f2bf(a.z); o[3] = (short)f2bf(a.w);
  o[4] = (short)f2bf(b.x); o[5] = (short)f2bf(b.y);
  o[6] = (short)f2bf(b.z); o[7] = (short)f2bf(b.w);
  *(short8*)(out + (size_t)i * 8) = o;
}

// ====== GEMM1: 256x128 tile, BK=32, 3-buf depth-2, 2 blocks/CU (r13) ======
__launch_bounds__(512, 4)
__global__ void gemm1_32(const ushort* __restrict__ A,
                         const ushort* __restrict__ B,
                         ushort* __restrict__ qkvb,
                         const int* __restrict__ msk,
                         int M, int N, int K) {
  __shared__ ushort sA[3][128 * 64];
  __shared__ ushort sB[3][64 * 64];

  const int tid = threadIdx.x;
  const int lane = tid & 63;
  const int wid = tid >> 6;
  const int wm = wid >> 2;
  const int wn = wid & 3;
  const int l15 = lane & 15;
  const int lg = lane >> 4;

  const int nbn = N >> 7;
  const int nwg = (M >> 8) * nbn;
  const int cpx = nwg >> 3;
  const int wg = (blockIdx.x & 7) * cpx + (blockIdx.x >> 3);
  const int bm = (wg / nbn) << 8;
  const int bn = (wg % nbn) << 7;

  f32x4 acc[8][2] = {};

  auto STAGE = [&](int buf, int kt) {
#pragma unroll
    for (int r = 0; r < 2; ++r) {
      int c = r * 512 + tid;
      int line = c >> 3, slot = c & 7;
      int ls = slot ^ (line & 7);
      int row = line * 2 + (ls >> 2), ci = ls & 3;
      gload_lds16(A + (size_t)(bm + row) * K + kt * 32 + ci * 8,
                  &sA[buf][c * 8]);
    }
    {
      int c = tid;
      int line = c >> 3, slot = c & 7;
      int ls = slot ^ (line & 7);
      int row = line * 2 + (ls >> 2), ci = ls & 3;
      gload_lds16(B + (size_t)(bn + row) * K + kt * 32 + ci * 8,
                  &sB[buf][c * 8]);
    }
  };

  const int nkt = K >> 5;
  STAGE(0, 0);
  STAGE(1, 1);

  int bufT = 0;
  for (int kt = 0; kt < nkt; ++kt) {
    if (kt + 1 < nkt) {
      asm volatile("s_waitcnt vmcnt(3)" ::: "memory");
    } else {
      asm volatile("s_waitcnt vmcnt(0)" ::: "memory");
    }
    __builtin_amdgcn_sched_barrier(0);
    __builtin_amdgcn_s_barrier();
    __builtin_amdgcn_sched_barrier(0);
    if (kt + 2 < nkt) {
      int nb = bufT + 2; if (nb >= 3) nb -= 3;
      STAGE(nb, kt + 2);
    }

    short8 bfr[2];
#pragma unroll
    for (int fc = 0; fc < 2; ++fc) {
      int R = wn * 32 + fc * 16 + l15;
      int line = R >> 1;
      int sl = (((R & 1) << 2) + lg) ^ (line & 7);
      bfr[fc] = *(const short8*)&sB[bufT][line * 64 + sl * 8];
    }
#pragma unroll
    for (int QQ = 0; QQ < 2; ++QQ) {
      short8 af[4];
#pragma unroll
      for (int fr = 0; fr < 4; ++fr) {
        int R = wm * 128 + (QQ * 4 + fr) * 16 + l15;
        int line = R >> 1;
        int sl = (((R & 1) << 2) + lg) ^ (line & 7);
        af[fr] = *(const short8*)&sA[bufT][line * 64 + sl * 8];
      }
      __builtin_amdgcn_s_setprio(1);
#pragma unroll
      for (int fr = 0; fr < 4; ++fr)
#pragma unroll
        for (int fc = 0; fc < 2; ++fc)
          acc[QQ * 4 + fr][fc] = __builtin_amdgcn_mfma_f32_16x16x32_bf16(
              af[fr], bfr[fc], acc[QQ * 4 + fr][fc], 0, 0, 0);
      __builtin_amdgcn_s_setprio(0);
    }
    bufT = (bufT + 1 == 3) ? 0 : bufT + 1;
  }

  const int b = bm >> 11;
#pragma unroll
  for (int ar = 0; ar < 8; ++ar) {
    int mk[4];
#pragma unroll
    for (int rr = 0; rr < 4; ++rr) {
      int gr = bm + wm * 128 + ar * 16 + lg * 4 + rr;
      mk[rr] = msk[b * T_SEQ + (gr & (T_SEQ - 1))];
    }
#pragma unroll
    for (int ac = 0; ac < 2; ++ac)
#pragma unroll
      for (int rr = 0; rr < 4; ++rr) {
        int gr = bm + wm * 128 + ar * 16 + lg * 4 + rr;
        int gc = bn + wn * 32 + ac * 16 + l15;
        int t = gr & (T_SEQ - 1);
        int h = gc / 192, rem = gc - h * 192;
        int sel = rem >> 6, d = rem & 63;
        size_t base = (size_t)((b * NHEAD + h) * 3 + sel) * T_SEQ * DHEAD;
        float v = acc[ar][ac][rr];
        size_t dst;
        if (sel == 2) {
          int tp = (t & ~63) | permInv(t & 63);
          if (!mk[rr]) v = 0.f;
          dst = base + (size_t)d * T_SEQ + tp;
        } else {
          dst = base + (size_t)t * DHEAD + d;
        }
        qkvb[dst] = f2bf(v);
      }
  }
}

// ====== GEMM2: 256x128 tile, BK=64, 3-buf depth-2 (r11 gemm3b) =============
__launch_bounds__(512, 1)
__global__ void gemm3b(const ushort* __restrict__ A,
                       const ushort* __restrict__ B,
                       float* __restrict__ Cout,
                       const float* __restrict__ bias,
                       int M, int N, int K) {
  __shared__ ushort sA[3][256 * 64];
  __shared__ ushort sB[3][128 * 64];

  const int tid = threadIdx.x;
  const int lane = tid & 63;
  const int wid = tid >> 6;
  const int wm = wid >> 2;
  const int wn = wid & 3;
  const int l15 = lane & 15;
  const int lg = lane >> 4;
  const int swz = l15 & 7;

  const int nbn = N >> 7;
  const int nwg = (M >> 8) * nbn;
  const int cpx = nwg >> 3;
  const int wg = (blockIdx.x & 7) * cpx + (blockIdx.x >> 3);
  const int bm = (wg / nbn) << 8;
  const int bn = (wg % nbn) << 7;

  f32x4 acc[8][2] = {};

  auto STAGE = [&](int buf, int kt) {
#pragma unroll
    for (int r = 0; r < 4; ++r) {
      int c = r * 512 + tid;
      int row = c >> 3, ci = c & 7;
      int sb = (ci ^ (row & 7)) * 8;
      gload_lds16(A + (size_t)(bm + row) * K + kt * 64 + sb, &sA[buf][c * 8]);
    }
#pragma unroll
    for (int r = 0; r < 2; ++r) {
      int c = r * 512 + tid;
      int row = c >> 3, ci = c & 7;
      int sb = (ci ^ (row & 7)) * 8;
      gload_lds16(B + (size_t)(bn + row) * K + kt * 64 + sb, &sB[buf][c * 8]);
    }
  };

  const int nkt = K >> 6;
  STAGE(0, 0);
  STAGE(1, 1);

  int bufT = 0;
  for (int kt = 0; kt < nkt; ++kt) {
    if (kt + 1 < nkt) {
      asm volatile("s_waitcnt vmcnt(6)" ::: "memory");
    } else {
      asm volatile("s_waitcnt vmcnt(0)" ::: "memory");
    }
    __builtin_amdgcn_sched_barrier(0);
    __builtin_amdgcn_s_barrier();
    __builtin_amdgcn_sched_barrier(0);
    if (kt + 2 < nkt) {
      int nb = bufT + 2; if (nb >= 3) nb -= 3;
      STAGE(nb, kt + 2);
    }

    short8 bfr[2][2];
#pragma unroll
    for (int fc = 0; fc < 2; ++fc)
#pragma unroll
      for (int ks = 0; ks < 2; ++ks)
        bfr[fc][ks] = *(const short8*)&sB[bufT][(wn * 32 + fc * 16 + l15) * 64 +
                                               ((ks * 4 + lg) ^ swz) * 8];
#pragma unroll
    for (int QQ = 0; QQ < 2; ++QQ) {
      short8 af[4][2];
#pragma unroll
      for (int fr = 0; fr < 4; ++fr)
#pragma unroll
        for (int ks = 0; ks < 2; ++ks)
          af[fr][ks] = *(const short8*)&sA[bufT][(wm * 128 + (QQ * 4 + fr) * 16 + l15) * 64 +
                                                ((ks * 4 + lg) ^ swz) * 8];
      __builtin_amdgcn_s_setprio(1);
#pragma unroll
      for (int fr = 0; fr < 4; ++fr)
#pragma unroll
        for (int fc = 0; fc < 2; ++fc)
#pragma unroll
          for (int ks = 0; ks < 2; ++ks)
            acc[QQ * 4 + fr][fc] = __builtin_amdgcn_mfma_f32_16x16x32_bf16(
                af[fr][ks], bfr[fc][ks], acc[QQ * 4 + fr][fc], 0, 0, 0);
      __builtin_amdgcn_s_setprio(0);
    }
    bufT = (bufT + 1 == 3) ? 0 : bufT + 1;
  }

#pragma unroll
  for (int ar = 0; ar < 8; ++ar)
#pragma unroll
    for (int ac = 0; ac < 2; ++ac) {
      int gc = bn + wn * 32 + ac * 16 + l15;
      float bv = bias[gc];
#pragma unroll
      for (int rr = 0; rr < 4; ++rr) {
        int gr = bm + wm * 128 + ar * 16 + lg * 4 + rr;
        Cout[(size_t)gr * N + gc] = acc[ar][ac][rr] + bv;
      }
    }
}

// ---------------- flash attention (two-tile pipeline, 64 q-rows/wave) ------
// qkv: Q,K = [bh*3+{0,1}][2048][64]; V^T = [bh*3+2][64][2048] (sigma-perm,
// mask-zeroed). 256 thr / 4 waves, 64 q-rows per wave -> QBLK=256/block,
// grid 512 = one exact dispatch round (2 blocks/CU). KVBLK=64.
// K/V fragment reads are wave-id-independent -> amortized over 2x MFMA.
// XCD remap: bh = ((bid>>6)<<3)|(bid&7), qt = (bid>>3)&7.
__launch_bounds__(256)
__global__ void attn_fwd(const ushort* __restrict__ qkv,
                         const int* __restrict__ mask,
                         ushort* __restrict__ attn) {
  __shared__ ushort sK[3][64 * 64];
  __shared__ ushort sVT[3][64 * 64];
  __shared__ ushort sInd[T_SEQ];

  const int tid = threadIdx.x;
  const int lane = tid & 63;
  const int wid = tid >> 6;
  const int l15 = lane & 15;
  const int lg = lane >> 4;
  const int bid = blockIdx.x;          // 0..511
  const int qt = (bid >> 3) & 7;       // 0..7
  const int bh = ((bid >> 6) << 3) | (bid & 7);  // 0..63
  const int b = bh >> 4, h = bh & 15;

  const ushort* Qp  = qkv + (size_t)(bh * 3 + 0) * T_SEQ * DHEAD;
  const ushort* Kp  = qkv + (size_t)(bh * 3 + 1) * T_SEQ * DHEAD;
  const ushort* VTp = qkv + (size_t)(bh * 3 + 2) * T_SEQ * DHEAD;
  const int* mrow = mask + b * T_SEQ;

  const int qbase = qt * 256 + wid * 64;

#pragma unroll
  for (int e = 0; e < 8; ++e) {
    int kv = tid * 8 + e;
    int p = (kv & ~63) | permInv(kv & 63);
    sInd[p] = mrow[kv] ? (ushort)0x3F80 : (ushort)0;
  }

  const float QSCALE = 0.18033688011112042f;
  short8 qf[4][2];
#pragma unroll
  for (int m = 0; m < 4; ++m)
#pragma unroll
    for (int ks = 0; ks < 2; ++ks) {
      short8 raw = *(const short8*)&Qp[(size_t)(qbase + m * 16 + l15) * 64 + ks * 32 + lg * 8];
#pragma unroll
      for (int e = 0; e < 8; ++e)
        qf[m][ks][e] = (short)f2bf(bf2f((ushort)raw[e]) * QSCALE);
    }

  f32x4 lacc[4] = {};
  f32x4 oacc[4][4] = {};   // [m][dt]

  auto STAGE = [&](int buf, int kt) {
    const int kb = kt * 64;
#pragma unroll
    for (int r2 = 0; r2 < 2; ++r2) {
      int c = r2 * 256 + tid;
      int row = c >> 3, ci = c & 7;
      int sb = (ci ^ (row & 7)) * 8;
      gload_lds16(Kp + (size_t)(kb + row) * 64 + sb, &sK[buf][c * 8]);
      gload_lds16(VTp + (size_t)row * T_SEQ + kb + sb, &sVT[buf][c * 8]);
    }
  };

  auto QKT = [&](int bufi, f32x4 (*st)[4]) {
    short8 kf0[4], kf1[4];
#pragma unroll
    for (int n = 0; n < 4; ++n) {
      kf0[n] = *(const short8*)&sK[bufi][(n * 16 + l15) * 64 + (((0 + lg) ^ (l15 & 7)) * 8)];
      kf1[n] = *(const short8*)&sK[bufi][(n * 16 + l15) * 64 + (((4 + lg) ^ (l15 & 7)) * 8)];
    }
    __builtin_amdgcn_s_setprio(1);
#pragma unroll
    for (int n = 0; n < 4; ++n)
#pragma unroll
      for (int m = 0; m < 4; ++m) {
        f32x4 z = {0.f, 0.f, 0.f, 0.f};
        st[n][m] = __builtin_amdgcn_mfma_f32_16x16x32_bf16(kf0[n], qf[m][0], z, 0, 0, 0);
        st[n][m] = __builtin_amdgcn_mfma_f32_16x16x32_bf16(kf1[n], qf[m][1], st[n][m], 0, 0, 0);
      }
    __builtin_amdgcn_s_setprio(0);
  };

  const int NT = T_SEQ / 64;

#define ATT_HALF(STC, STN, T, BC, BN_, BS)                                   \
  {                                                                          \
    _Pragma("unroll")                                                        \
    for (int m = 0; m < 4; ++m)                                              \
      _Pragma("unroll")                                                      \
      for (int n = 0; n < 4; ++n)                                            \
        _Pragma("unroll")                                                    \
        for (int r = 0; r < 4; ++r)                                          \
          STC[n][m][r] = EXP2(STC[n][m][r]);                                 \
    short8 pa[4][2];                                                         \
    _Pragma("unroll")                                                        \
    for (int m = 0; m < 4; ++m)                                              \
      _Pragma("unroll")                                                      \
      for (int ks = 0; ks < 2; ++ks)                                         \
        _Pragma("unroll")                                                    \
        for (int e = 0; e < 4; ++e) {                                        \
          pa[m][ks][e]     = (short)f2bf(STC[ks * 2][m][e]);                 \
          pa[m][ks][4 + e] = (short)f2bf(STC[ks * 2 + 1][m][e]);             \
        }                                                                    \
    asm volatile("s_waitcnt vmcnt(0)" ::: "memory");                         \
    __builtin_amdgcn_sched_barrier(0);                                       \
    __builtin_amdgcn_s_barrier();                                            \
    if ((T) + 2 < NT) STAGE(BS, (T) + 2);                                    \
    if ((T) + 1 < NT) QKT(BN_, STN);                                         \
    _Pragma("unroll")                                                        \
    for (int ks = 0; ks < 2; ++ks) {                                         \
      short8 vf[4];                                                          \
      _Pragma("unroll")                                                      \
      for (int dt = 0; dt < 4; ++dt)                                         \
        vf[dt] = *(const short8*)&sVT[BC][(dt * 16 + l15) * 64 +             \
                 (((ks * 4 + lg) ^ (l15 & 7)) * 8)];                         \
      short8 vi = *(const short8*)&sInd[(T) * 64 + ks * 32 + lg * 8];        \
      __builtin_amdgcn_s_setprio(1);                                         \
      _Pragma("unroll")                                                      \
      for (int dt = 0; dt < 4; ++dt)                                         \
        _Pragma("unroll")                                                    \
        for (int m = 0; m < 4; ++m)                                          \
          oacc[m][dt] = __builtin_amdgcn_mfma_f32_16x16x32_bf16(             \
              vf[dt], pa[m][ks], oacc[m][dt], 0, 0, 0);                      \
      _Pragma("unroll")                                                      \
      for (int m = 0; m < 4; ++m)                                            \
        lacc[m] = __builtin_amdgcn_mfma_f32_16x16x32_bf16(                   \
            vi, pa[m][ks], lacc[m], 0, 0, 0);                                \
      __builtin_amdgcn_s_setprio(0);                                         \
    }                                                                        \
  }

  STAGE(0, 0);
  STAGE(1, 1);
  __syncthreads();

  f32x4 stA[4][4], stB[4][4];
  QKT(0, stA);

  int cur = 0;
  for (int kt = 0; kt < NT; kt += 2) {
    int b1 = cur + 1; if (b1 >= 3) b1 -= 3;
    int b2 = cur + 2; if (b2 >= 3) b2 -= 3;
    ATT_HALF(stA, stB, kt,     cur, b1, b2);
    ATT_HALF(stB, stA, kt + 1, b1,  b2, cur);
    cur = b2;
  }
#undef ATT_HALF

#pragma unroll
  for (int m = 0; m < 4; ++m) {
    float rl = 1.0f / lacc[m][0];
    int t = qbase + m * 16 + l15;
#pragma unroll
    for (int dt = 0; dt < 4; ++dt) {
      short4b ov;
#pragma unroll
      for (int r = 0; r < 4; ++r) ov[r] = (short)f2bf(oacc[m][dt][r] * rl);
      *(short4b*)&attn[(size_t)(b * T_SEQ + t) * DMODEL + h * DHEAD + dt * 16 + lg * 4] = ov;
    }
  }
}

// ---------------- launch ----------------
extern "C" void kernel_launch(void* const* d_in, const int* in_sizes, int n_in,
                              void* d_out, int out_size, void* d_ws, size_t ws_size,
                              hipStream_t stream) {
  (void)in_sizes; (void)n_in; (void)out_size; (void)ws_size;
  const float* x      = (const float*)d_in[0];  // [4,2048,1024]
  const int*   mask   = (const int*)d_in[1];    // [4,2048]
  const float* w_qkv  = (const float*)d_in[2];  // [3072,1024]
  const float* w_tail = (const float*)d_in[3];  // [1024,1024]
  const float* b_tail = (const float*)d_in[4];  // [1024]
  float* out = (float*)d_out;

  const size_t M = 4 * 2048;
  ushort* xb     = (ushort*)d_ws;                    // 8192*1024
  ushort* wqkvb  = xb + M * DMODEL;                  // 3072*1024
  ushort* wtailb = wqkvb + 3 * DMODEL * DMODEL;      // 1024*1024
  ushort* qkvb   = wtailb + DMODEL * DMODEL;         // 64*3*2048*64
  ushort* attnb  = qkvb + (size_t)64 * 3 * T_SEQ * DHEAD;  // 8192*1024

  {
    int n8x = (int)(M * DMODEL / 8);
    int n8q = 3 * DMODEL * DMODEL / 8;
    int n8t = DMODEL * DMODEL / 8;
    int n8 = n8x + n8q + n8t;
    cvt_all<<<(n8 + 255) / 256, 256, 0, stream>>>(x, w_qkv, w_tail, xb, n8x, n8q, n8t);
  }

  // GEMM1 (256x128, BK=32, 2 blocks/CU): qkv = x @ w_qkv^T; grid 768
  gemm1_32<<<dim3((M / 256) * (3 * DMODEL / 128)), 512, 0, stream>>>(
      xb, wqkvb, qkvb, mask, (int)M, 3 * DMODEL, DMODEL);

  // attention (grid 512 = one exact round, XCD-aware bh mapping)
  attn_fwd<<<dim3(512), 256, 0, stream>>>(qkvb, mask, attnb);

  // GEMM2 (256x128, BK=64): out = attn @ w_tail^T + b_tail; grid 256
  gemm3b<<<dim3((M / 256) * (DMODEL / 128)), 512, 0, stream>>>(
      attnb, wtailb, out, b_tail, (int)M, DMODEL, DMODEL);
}

// Round 15
// 210.346 us; speedup vs baseline: 1.0850x; 1.0850x over previous
//
#include <hip/hip_runtime.h>
#include <hip/hip_bf16.h>
#include <stdint.h>

// MultiHeadAttention: x[4,2048,1024] fp32, mask[4,2048] i32,
// w_qkv[3072,1024], w_tail[1024,1024], b_tail[1024] -> out[4,2048,1024] fp32
// Pipeline: fused cvt->bf16; GEMM1 = 256x128 BK=32 depth-2 (2 blocks/CU);
// GEMM2 = 128x128 BK=32 depth-2 (2 blocks/CU, grid 512 = 1 exact round);
// attn = r13 two-tile pipeline (32 q-rows/wave, VGPR 116 — r14's 64-row
// variant blew VGPR to 200 and regressed; reverted).

typedef __attribute__((ext_vector_type(8))) short short8;
typedef __attribute__((ext_vector_type(4))) short short4b;
typedef __attribute__((ext_vector_type(4))) float f32x4;

#define T_SEQ 2048
#define NHEAD 16
#define DHEAD 64
#define DMODEL 1024

#if __has_builtin(__builtin_amdgcn_exp2f)
#define EXP2(x) __builtin_amdgcn_exp2f(x)
#else
#define EXP2(x) exp2f(x)
#endif

__device__ __forceinline__ ushort f2bf(float f) {
  __bf16 h = (__bf16)f;
  unsigned short u;
  __builtin_memcpy(&u, &h, 2);
  return u;
}
__device__ __forceinline__ float bf2f(ushort b) {
  return __uint_as_float(((uint32_t)b) << 16);
}

// sigma-perm within a 64-column tile; inverse (kv -> stored pos):
__device__ __forceinline__ int permInv(int x) {
  return (x & 0x23) | ((x & 0x0C) << 1) | ((x & 0x10) >> 2);
}

__device__ __forceinline__ void gload_lds16(const ushort* g, ushort* l) {
  __builtin_amdgcn_global_load_lds(
      (const __attribute__((address_space(1))) void*)g,
      (__attribute__((address_space(3))) void*)l, 16, 0, 0);
}

// ---------------- fused fp32 -> bf16 conversion (x | w_qkv | w_tail) -------
__global__ void cvt_all(const float* __restrict__ x,
                        const float* __restrict__ wq,
                        const float* __restrict__ wt,
                        ushort* __restrict__ out,
                        int n8x, int n8q, int n8t) {
  int i = blockIdx.x * blockDim.x + threadIdx.x;
  const float* src;
  int j;
  if (i < n8x) { src = x; j = i; }
  else if (i < n8x + n8q) { src = wq; j = i - n8x; }
  else if (i < n8x + n8q + n8t) { src = wt; j = i - n8x - n8q; }
  else return;
  const float4* p = (const float4*)(src + (size_t)j * 8);
  float4 a = p[0], b = p[1];
  short8 o;
  o[0] = (short)f2bf(a.x); o[1] = (short)f2bf(a.y);
  o[2] = (short)f2bf(a.z); o[3] = (short)f2bf(a.w);
  o[4] = (short)f2bf(b.x); o[5] = (short)f2bf(b.y);
  o[6] = (short)f2bf(b.z); o[7] = (short)f2bf(b.w);
  *(short8*)(out + (size_t)i * 8) = o;
}

// ====== GEMM1: 256x128 tile, BK=32, 3-buf depth-2, 2 blocks/CU (r13) ======
__launch_bounds__(512, 4)
__global__ void gemm1_32(const ushort* __restrict__ A,
                         const ushort* __restrict__ B,
                         ushort* __restrict__ qkvb,
                         const int* __restrict__ msk,
                         int M, int N, int K) {
  __shared__ ushort sA[3][128 * 64];
  __shared__ ushort sB[3][64 * 64];

  const int tid = threadIdx.x;
  const int lane = tid & 63;
  const int wid = tid >> 6;
  const int wm = wid >> 2;
  const int wn = wid & 3;
  const int l15 = lane & 15;
  const int lg = lane >> 4;

  const int nbn = N >> 7;
  const int nwg = (M >> 8) * nbn;
  const int cpx = nwg >> 3;
  const int wg = (blockIdx.x & 7) * cpx + (blockIdx.x >> 3);
  const int bm = (wg / nbn) << 8;
  const int bn = (wg % nbn) << 7;

  f32x4 acc[8][2] = {};

  auto STAGE = [&](int buf, int kt) {
#pragma unroll
    for (int r = 0; r < 2; ++r) {
      int c = r * 512 + tid;
      int line = c >> 3, slot = c & 7;
      int ls = slot ^ (line & 7);
      int row = line * 2 + (ls >> 2), ci = ls & 3;
      gload_lds16(A + (size_t)(bm + row) * K + kt * 32 + ci * 8,
                  &sA[buf][c * 8]);
    }
    {
      int c = tid;
      int line = c >> 3, slot = c & 7;
      int ls = slot ^ (line & 7);
      int row = line * 2 + (ls >> 2), ci = ls & 3;
      gload_lds16(B + (size_t)(bn + row) * K + kt * 32 + ci * 8,
                  &sB[buf][c * 8]);
    }
  };

  const int nkt = K >> 5;
  STAGE(0, 0);
  STAGE(1, 1);

  int bufT = 0;
  for (int kt = 0; kt < nkt; ++kt) {
    if (kt + 1 < nkt) {
      asm volatile("s_waitcnt vmcnt(3)" ::: "memory");
    } else {
      asm volatile("s_waitcnt vmcnt(0)" ::: "memory");
    }
    __builtin_amdgcn_sched_barrier(0);
    __builtin_amdgcn_s_barrier();
    __builtin_amdgcn_sched_barrier(0);
    if (kt + 2 < nkt) {
      int nb = bufT + 2; if (nb >= 3) nb -= 3;
      STAGE(nb, kt + 2);
    }

    short8 bfr[2];
#pragma unroll
    for (int fc = 0; fc < 2; ++fc) {
      int R = wn * 32 + fc * 16 + l15;
      int line = R >> 1;
      int sl = (((R & 1) << 2) + lg) ^ (line & 7);
      bfr[fc] = *(const short8*)&sB[bufT][line * 64 + sl * 8];
    }
#pragma unroll
    for (int QQ = 0; QQ < 2; ++QQ) {
      short8 af[4];
#pragma unroll
      for (int fr = 0; fr < 4; ++fr) {
        int R = wm * 128 + (QQ * 4 + fr) * 16 + l15;
        int line = R >> 1;
        int sl = (((R & 1) << 2) + lg) ^ (line & 7);
        af[fr] = *(const short8*)&sA[bufT][line * 64 + sl * 8];
      }
      __builtin_amdgcn_s_setprio(1);
#pragma unroll
      for (int fr = 0; fr < 4; ++fr)
#pragma unroll
        for (int fc = 0; fc < 2; ++fc)
          acc[QQ * 4 + fr][fc] = __builtin_amdgcn_mfma_f32_16x16x32_bf16(
              af[fr], bfr[fc], acc[QQ * 4 + fr][fc], 0, 0, 0);
      __builtin_amdgcn_s_setprio(0);
    }
    bufT = (bufT + 1 == 3) ? 0 : bufT + 1;
  }

  const int b = bm >> 11;
#pragma unroll
  for (int ar = 0; ar < 8; ++ar) {
    int mk[4];
#pragma unroll
    for (int rr = 0; rr < 4; ++rr) {
      int gr = bm + wm * 128 + ar * 16 + lg * 4 + rr;
      mk[rr] = msk[b * T_SEQ + (gr & (T_SEQ - 1))];
    }
#pragma unroll
    for (int ac = 0; ac < 2; ++ac)
#pragma unroll
      for (int rr = 0; rr < 4; ++rr) {
        int gr = bm + wm * 128 + ar * 16 + lg * 4 + rr;
        int gc = bn + wn * 32 + ac * 16 + l15;
        int t = gr & (T_SEQ - 1);
        int h = gc / 192, rem = gc - h * 192;
        int sel = rem >> 6, d = rem & 63;
        size_t base = (size_t)((b * NHEAD + h) * 3 + sel) * T_SEQ * DHEAD;
        float v = acc[ar][ac][rr];
        size_t dst;
        if (sel == 2) {
          int tp = (t & ~63) | permInv(t & 63);
          if (!mk[rr]) v = 0.f;
          dst = base + (size_t)d * T_SEQ + tp;
        } else {
          dst = base + (size_t)t * DHEAD + d;
        }
        qkvb[dst] = f2bf(v);
      }
  }
}

// ====== GEMM2: 128x128 tile, BK=32, 3-buf depth-2, 2 blocks/CU =============
// grid 512 = one exact round at 2 blocks/CU (48 KB LDS). 8 waves (2M x 4N),
// wave tile 64x32 (acc[4][2]), 8 MFMA/K-tile. STAGE = 2 loads/thread ->
// steady-state wait vmcnt(2). Same pair-packed swizzled 128B lines as GEMM1.
__launch_bounds__(512, 4)
__global__ void gemm2_128(const ushort* __restrict__ A,
                          const ushort* __restrict__ B,
                          float* __restrict__ Cout,
                          const float* __restrict__ bias,
                          int M, int N, int K) {
  __shared__ ushort sA[3][64 * 64];    // 128 rows x 32 cols, pair-packed
  __shared__ ushort sB[3][64 * 64];

  const int tid = threadIdx.x;
  const int lane = tid & 63;
  const int wid = tid >> 6;
  const int wm = wid >> 2;             // 0..1 (64-row half)
  const int wn = wid & 3;              // 0..3 (32-col quarter)
  const int l15 = lane & 15;
  const int lg = lane >> 4;

  // bijective XCD remap (nwg = 64*8 = 512, %8==0)
  const int nbn = N >> 7;              // 8
  const int nwg = (M >> 7) * nbn;      // 512
  const int cpx = nwg >> 3;
  const int wg = (blockIdx.x & 7) * cpx + (blockIdx.x >> 3);
  const int bm = (wg / nbn) << 7;
  const int bn = (wg % nbn) << 7;

  f32x4 acc[4][2] = {};

  auto STAGE = [&](int buf, int kt) {
    {
      int c = tid;
      int line = c >> 3, slot = c & 7;
      int ls = slot ^ (line & 7);
      int row = line * 2 + (ls >> 2), ci = ls & 3;
      gload_lds16(A + (size_t)(bm + row) * K + kt * 32 + ci * 8,
                  &sA[buf][c * 8]);
    }
    {
      int c = tid;
      int line = c >> 3, slot = c & 7;
      int ls = slot ^ (line & 7);
      int row = line * 2 + (ls >> 2), ci = ls & 3;
      gload_lds16(B + (size_t)(bn + row) * K + kt * 32 + ci * 8,
                  &sB[buf][c * 8]);
    }
  };

  const int nkt = K >> 5;              // 32
  STAGE(0, 0);
  STAGE(1, 1);

  int bufT = 0;
  for (int kt = 0; kt < nkt; ++kt) {
    if (kt + 1 < nkt) {
      asm volatile("s_waitcnt vmcnt(2)" ::: "memory");  // T landed, T+1 aloft
    } else {
      asm volatile("s_waitcnt vmcnt(0)" ::: "memory");
    }
    __builtin_amdgcn_sched_barrier(0);
    __builtin_amdgcn_s_barrier();
    __builtin_amdgcn_sched_barrier(0);
    if (kt + 2 < nkt) {
      int nb = bufT + 2; if (nb >= 3) nb -= 3;
      STAGE(nb, kt + 2);
    }

    short8 bfr[2];
#pragma unroll
    for (int fc = 0; fc < 2; ++fc) {
      int R = wn * 32 + fc * 16 + l15;
      int line = R >> 1;
      int sl = (((R & 1) << 2) + lg) ^ (line & 7);
      bfr[fc] = *(const short8*)&sB[bufT][line * 64 + sl * 8];
    }
    short8 af[4];
#pragma unroll
    for (int fr = 0; fr < 4; ++fr) {
      int R = wm * 64 + fr * 16 + l15;
      int line = R >> 1;
      int sl = (((R & 1) << 2) + lg) ^ (line & 7);
      af[fr] = *(const short8*)&sA[bufT][line * 64 + sl * 8];
    }
    __builtin_amdgcn_s_setprio(1);
#pragma unroll
    for (int fr = 0; fr < 4; ++fr)
#pragma unroll
      for (int fc = 0; fc < 2; ++fc)
        acc[fr][fc] = __builtin_amdgcn_mfma_f32_16x16x32_bf16(
            af[fr], bfr[fc], acc[fr][fc], 0, 0, 0);
    __builtin_amdgcn_s_setprio(0);
    bufT = (bufT + 1 == 3) ? 0 : bufT + 1;
  }

#pragma unroll
  for (int fr = 0; fr < 4; ++fr)
#pragma unroll
    for (int fc = 0; fc < 2; ++fc) {
      int gc = bn + wn * 32 + fc * 16 + l15;
      float bv = bias[gc];
#pragma unroll
      for (int rr = 0; rr < 4; ++rr) {
        int gr = bm + wm * 64 + fr * 16 + lg * 4 + rr;
        Cout[(size_t)gr * N + gc] = acc[fr][fc][rr] + bv;
      }
    }
}

// ---------------- flash attention (two-tile pipeline, r13 exact) -----------
// 256 thr / 4 waves, 32 q-rows/wave (QBLK=128), grid 1024, VGPR ~116.
__launch_bounds__(256)
__global__ void attn_fwd(const ushort* __restrict__ qkv,
                         const int* __restrict__ mask,
                         ushort* __restrict__ attn) {
  __shared__ ushort sK[3][64 * 64];
  __shared__ ushort sVT[3][64 * 64];
  __shared__ ushort sInd[T_SEQ];

  const int tid = threadIdx.x;
  const int lane = tid & 63;
  const int wid = tid >> 6;
  const int l15 = lane & 15;
  const int lg = lane >> 4;
  const int bid = blockIdx.x;
  const int qt = (bid >> 3) & 15;
  const int bh = ((bid >> 7) << 3) | (bid & 7);
  const int b = bh >> 4, h = bh & 15;

  const ushort* Qp  = qkv + (size_t)(bh * 3 + 0) * T_SEQ * DHEAD;
  const ushort* Kp  = qkv + (size_t)(bh * 3 + 1) * T_SEQ * DHEAD;
  const ushort* VTp = qkv + (size_t)(bh * 3 + 2) * T_SEQ * DHEAD;
  const int* mrow = mask + b * T_SEQ;

  const int qbase = qt * 128 + wid * 32;

#pragma unroll
  for (int e = 0; e < 8; ++e) {
    int kv = tid * 8 + e;
    int p = (kv & ~63) | permInv(kv & 63);
    sInd[p] = mrow[kv] ? (ushort)0x3F80 : (ushort)0;
  }

  const float QSCALE = 0.18033688011112042f;
  short8 qf[2][2];
#pragma unroll
  for (int m = 0; m < 2; ++m)
#pragma unroll
    for (int ks = 0; ks < 2; ++ks) {
      short8 raw = *(const short8*)&Qp[(size_t)(qbase + m * 16 + l15) * 64 + ks * 32 + lg * 8];
#pragma unroll
      for (int e = 0; e < 8; ++e)
        qf[m][ks][e] = (short)f2bf(bf2f((ushort)raw[e]) * QSCALE);
    }

  f32x4 lacc[2] = {};
  f32x4 oacc[2][4] = {};

  auto STAGE = [&](int buf, int kt) {
    const int kb = kt * 64;
#pragma unroll
    for (int r2 = 0; r2 < 2; ++r2) {
      int c = r2 * 256 + tid;
      int row = c >> 3, ci = c & 7;
      int sb = (ci ^ (row & 7)) * 8;
      gload_lds16(Kp + (size_t)(kb + row) * 64 + sb, &sK[buf][c * 8]);
      gload_lds16(VTp + (size_t)row * T_SEQ + kb + sb, &sVT[buf][c * 8]);
    }
  };

  auto QKT = [&](int bufi, f32x4 (*st)[2]) {
    short8 kf0[4], kf1[4];
#pragma unroll
    for (int n = 0; n < 4; ++n) {
      kf0[n] = *(const short8*)&sK[bufi][(n * 16 + l15) * 64 + (((0 + lg) ^ (l15 & 7)) * 8)];
      kf1[n] = *(const short8*)&sK[bufi][(n * 16 + l15) * 64 + (((4 + lg) ^ (l15 & 7)) * 8)];
    }
    __builtin_amdgcn_s_setprio(1);
#pragma unroll
    for (int n = 0; n < 4; ++n)
#pragma unroll
      for (int m = 0; m < 2; ++m) {
        f32x4 z = {0.f, 0.f, 0.f, 0.f};
        st[n][m] = __builtin_amdgcn_mfma_f32_16x16x32_bf16(kf0[n], qf[m][0], z, 0, 0, 0);
        st[n][m] = __builtin_amdgcn_mfma_f32_16x16x32_bf16(kf1[n], qf[m][1], st[n][m], 0, 0, 0);
      }
    __builtin_amdgcn_s_setprio(0);
  };

  const int NT = T_SEQ / 64;

#define ATT_HALF(STC, STN, T, BC, BN_, BS)                                   \
  {                                                                          \
    _Pragma("unroll")                                                        \
    for (int m = 0; m < 2; ++m)                                              \
      _Pragma("unroll")                                                      \
      for (int n = 0; n < 4; ++n)                                            \
        _Pragma("unroll")                                                    \
        for (int r = 0; r < 4; ++r)                                          \
          STC[n][m][r] = EXP2(STC[n][m][r]);                                 \
    short8 pa[2][2];                                                         \
    _Pragma("unroll")                                                        \
    for (int m = 0; m < 2; ++m)                                              \
      _Pragma("unroll")                                                      \
      for (int ks = 0; ks < 2; ++ks)                                         \
        _Pragma("unroll")                                                    \
        for (int e = 0; e < 4; ++e) {                                        \
          pa[m][ks][e]     = (short)f2bf(STC[ks * 2][m][e]);                 \
          pa[m][ks][4 + e] = (short)f2bf(STC[ks * 2 + 1][m][e]);             \
        }                                                                    \
    asm volatile("s_waitcnt vmcnt(0)" ::: "memory");                         \
    __builtin_amdgcn_sched_barrier(0);                                       \
    __builtin_amdgcn_s_barrier();                                            \
    if ((T) + 2 < NT) STAGE(BS, (T) + 2);                                    \
    if ((T) + 1 < NT) QKT(BN_, STN);                                         \
    _Pragma("unroll")                                                        \
    for (int ks = 0; ks < 2; ++ks) {                                         \
      short8 vf[4];                                                          \
      _Pragma("unroll")                                                      \
      for (int dt = 0; dt < 4; ++dt)                                         \
        vf[dt] = *(const short8*)&sVT[BC][(dt * 16 + l15) * 64 +             \
                 (((ks * 4 + lg) ^ (l15 & 7)) * 8)];                         \
      short8 vi = *(const short8*)&sInd[(T) * 64 + ks * 32 + lg * 8];        \
      __builtin_amdgcn_s_setprio(1);                                         \
      _Pragma("unroll")                                                      \
      for (int dt = 0; dt < 4; ++dt)                                         \
        _Pragma("unroll")                                                    \
        for (int m = 0; m < 2; ++m)                                          \
          oacc[m][dt] = __builtin_amdgcn_mfma_f32_16x16x32_bf16(             \
              vf[dt], pa[m][ks], oacc[m][dt], 0, 0, 0);                      \
      _Pragma("unroll")                                                      \
      for (int m = 0; m < 2; ++m)                                            \
        lacc[m] = __builtin_amdgcn_mfma_f32_16x16x32_bf16(                   \
            vi, pa[m][ks], lacc[m], 0, 0, 0);                                \
      __builtin_amdgcn_s_setprio(0);                                         \
    }                                                                        \
  }

  STAGE(0, 0);
  STAGE(1, 1);
  __syncthreads();

  f32x4 stA[4][2], stB[4][2];
  QKT(0, stA);

  int cur = 0;
  for (int kt = 0; kt < NT; kt += 2) {
    int b1 = cur + 1; if (b1 >= 3) b1 -= 3;
    int b2 = cur + 2; if (b2 >= 3) b2 -= 3;
    ATT_HALF(stA, stB, kt,     cur, b1, b2);
    ATT_HALF(stB, stA, kt + 1, b1,  b2, cur);
    cur = b2;
  }
#undef ATT_HALF

#pragma unroll
  for (int m = 0; m < 2; ++m) {
    float rl = 1.0f / lacc[m][0];
    int t = qbase + m * 16 + l15;
#pragma unroll
    for (int dt = 0; dt < 4; ++dt) {
      short4b ov;
#pragma unroll
      for (int r = 0; r < 4; ++r) ov[r] = (short)f2bf(oacc[m][dt][r] * rl);
      *(short4b*)&attn[(size_t)(b * T_SEQ + t) * DMODEL + h * DHEAD + dt * 16 + lg * 4] = ov;
    }
  }
}

// ---------------- launch ----------------
extern "C" void kernel_launch(void* const* d_in, const int* in_sizes, int n_in,
                              void* d_out, int out_size, void* d_ws, size_t ws_size,
                              hipStream_t stream) {
  (void)in_sizes; (void)n_in; (void)out_size; (void)ws_size;
  const float* x      = (const float*)d_in[0];  // [4,2048,1024]
  const int*   mask   = (const int*)d_in[1];    // [4,2048]
  const float* w_qkv  = (const float*)d_in[2];  // [3072,1024]
  const float* w_tail = (const float*)d_in[3];  // [1024,1024]
  const float* b_tail = (const float*)d_in[4];  // [1024]
  float* out = (float*)d_out;

  const size_t M = 4 * 2048;
  ushort* xb     = (ushort*)d_ws;                    // 8192*1024
  ushort* wqkvb  = xb + M * DMODEL;                  // 3072*1024
  ushort* wtailb = wqkvb + 3 * DMODEL * DMODEL;      // 1024*1024
  ushort* qkvb   = wtailb + DMODEL * DMODEL;         // 64*3*2048*64
  ushort* attnb  = qkvb + (size_t)64 * 3 * T_SEQ * DHEAD;  // 8192*1024

  {
    int n8x = (int)(M * DMODEL / 8);
    int n8q = 3 * DMODEL * DMODEL / 8;
    int n8t = DMODEL * DMODEL / 8;
    int n8 = n8x + n8q + n8t;
    cvt_all<<<(n8 + 255) / 256, 256, 0, stream>>>(x, w_qkv, w_tail, xb, n8x, n8q, n8t);
  }

  // GEMM1 (256x128, BK=32, 2 blocks/CU): qkv = x @ w_qkv^T; grid 768
  gemm1_32<<<dim3((M / 256) * (3 * DMODEL / 128)), 512, 0, stream>>>(
      xb, wqkvb, qkvb, mask, (int)M, 3 * DMODEL, DMODEL);

  // attention (grid 1024, XCD-aware bh mapping) — r13 version
  attn_fwd<<<dim3(1024), 256, 0, stream>>>(qkvb, mask, attnb);

  // GEMM2 (128x128, BK=32, 2 blocks/CU): out = attn @ w_tail^T + b_tail; grid 512
  gemm2_128<<<dim3((M / 128) * (DMODEL / 128)), 512, 0, stream>>>(
      attnb, wtailb, out, b_tail, (int)M, DMODEL, DMODEL);
}